// Round 5
// baseline (218.434 us; speedup 1.0000x reference)
//
#include <hip/hip_runtime.h>
#include <hip/hip_bf16.h>
#include <stdint.h>

#define NR 384          // total rows
#define DD 73728        // C*H*W
#define PDV 16          // N_PARTS * N_DATASETS
#define BSV 192         // batch size
#define KSPLIT 128      // split-K factor (768 blocks = 3/CU, fully resident)
#define KCH 576         // DD / KSPLIT
#define BK 32           // K-tile per iteration
#define NIT 18          // KCH / BK
#define RS 40           // LDS row stride bf16 (80 B = 20 banks, 16B-aligned)

typedef __bf16 bf16;
typedef __attribute__((ext_vector_type(4))) __bf16 bf16x4;
typedef __attribute__((ext_vector_type(8))) __bf16 bf16x8;
typedef __attribute__((ext_vector_type(4))) float f32x4;

// ---------------------------------------------------------------- kernel 1
// Fused demean + cast + partial Gram. R5 change vs R4: DEPTH-2 register
// prefetch. R4 issued tile it+1's X loads one iteration (~600-800 cyc)
// before write_tiles consumed them -- short of the ~900-cyc HBM latency for
// the 48 KB/XCD of FRESH lines each iteration touches, so every iter the
// barrier convoy ate the latency tail (~25 us total). Two named register
// sets (A=even tiles, B=odd tiles) give each load ~2 iterations in flight.
// Macro-expanded sets: every array index is compile-time (no scratch).
// Load order / demean math / LDS layout / MFMA order are byte-identical to
// R4 -> bit-identical Gp.
__global__ __launch_bounds__(256, 3) void k_gram(const float* __restrict__ X,
                                                 const float* __restrict__ M,
                                                 float* __restrict__ Gp) {
    __shared__ float msh[4 * KCH];       // 9.2 KB
    __shared__ bf16 ash[2][128 * RS];    // 20 KB
    __shared__ bf16 bsh[2][128 * RS];    // 20 KB  (total 49.2 KB, 3/CU OK)
    const int tid  = threadIdx.x;
    const int lane = tid & 63;
    const int w    = tid >> 6;
    const int quad = lane >> 4;
    const int l15  = lane & 15;
    const int wm   = w & 1, wn = w >> 1;
    const int srow = tid >> 3;           // staging row base 0..31
    const int fseg = tid & 7;            // 16B segment within 128B row-chunk
    const int mds  = (srow >> 2) & 3;    // dataset id (same for all p)

    int xcd  = blockIdx.x & 7;
    int g    = blockIdx.x >> 3;
    int tile = g % 6;
    int ks   = xcd + 8 * (g / 6);        // 6 tiles of one ks share an XCD
    int tm = (tile < 3) ? 0 : ((tile < 5) ? 1 : 2);
    int tn = (tile < 3) ? tile : ((tile < 5) ? (tile - 2) : 2);
    const bool diag = (tm == tn);
    const float* Xa = X + (size_t)(tm * 128) * DD;
    const float* Xb = X + (size_t)(tn * 128) * DD;
    size_t k0 = (size_t)ks * KCH;

    // ---- stage M slice once: 4 datasets x 576 floats
    for (int i = tid; i < 4 * 144; i += 256) {
        int ds = i / 144;
        int c  = (i - ds * 144) * 4;
        *(float4*)&msh[ds * KCH + c] = *(const float4*)(M + (size_t)ds * DD + k0 + c);
    }

    f32x4 acc[4][4];
#pragma unroll
    for (int i = 0; i < 4; ++i)
#pragma unroll
        for (int j = 0; j < 4; ++j) acc[i][j] = (f32x4){0.f, 0.f, 0.f, 0.f};

    float4 xaA[4], xbA[4], xaB[4], xbB[4];   // two named staging sets

#define LOAD_SET(XA, XB, IT)                                               \
    {                                                                      \
        size_t gk = k0 + (size_t)(IT) * BK + fseg * 4;                     \
        _Pragma("unroll")                                                  \
        for (int p = 0; p < 4; ++p) {                                      \
            int row = p * 32 + srow;                                       \
            XA[p] = *(const float4*)(Xa + (size_t)row * DD + gk);          \
            if (!diag) XB[p] = *(const float4*)(Xb + (size_t)row * DD + gk); \
        }                                                                  \
    }

#define WRITE_SET(XA, XB, IT, BUF)                                         \
    {                                                                      \
        int kc = (IT) * BK + fseg * 4;                                     \
        float4 m4 = *(const float4*)&msh[mds * KCH + kc];                  \
        _Pragma("unroll")                                                  \
        for (int p = 0; p < 4; ++p) {                                      \
            int row = p * 32 + srow;                                       \
            bf16x4 za;                                                     \
            za[0] = (bf16)(XA[p].x - m4.x); za[1] = (bf16)(XA[p].y - m4.y); \
            za[2] = (bf16)(XA[p].z - m4.z); za[3] = (bf16)(XA[p].w - m4.w); \
            *(bf16x4*)&ash[BUF][row * RS + fseg * 4] = za;                 \
            if (!diag) {                                                   \
                bf16x4 zb;                                                 \
                zb[0] = (bf16)(XB[p].x - m4.x); zb[1] = (bf16)(XB[p].y - m4.y); \
                zb[2] = (bf16)(XB[p].z - m4.z); zb[3] = (bf16)(XB[p].w - m4.w); \
                *(bf16x4*)&bsh[BUF][row * RS + fseg * 4] = zb;             \
            }                                                              \
        }                                                                  \
    }

    auto compute = [&](int buf) {
        const bf16* bb = diag ? ash[buf] : bsh[buf];
        bf16x8 af[4], bfv[4];
#pragma unroll
        for (int i = 0; i < 4; ++i) {
            int r = wm * 64 + i * 16 + l15;
            af[i] = *(const bf16x8*)&ash[buf][r * RS + quad * 8];
        }
#pragma unroll
        for (int j = 0; j < 4; ++j) {
            int r = wn * 64 + j * 16 + l15;
            bfv[j] = *(const bf16x8*)&bb[r * RS + quad * 8];
        }
#pragma unroll
        for (int i = 0; i < 4; ++i)
#pragma unroll
            for (int j = 0; j < 4; ++j)
                acc[i][j] = __builtin_amdgcn_mfma_f32_16x16x32_bf16(
                    af[i], bfv[j], acc[i][j], 0, 0, 0);
    };

    // prologue: A <- tile0; stage tile0; B <- tile1; A <- tile2 (in flight)
    LOAD_SET(xaA, xbA, 0);
    __syncthreads();              // msh visible
    WRITE_SET(xaA, xbA, 0, 0);    // vmcnt drains tile-0 loads only
    LOAD_SET(xaB, xbB, 1);
    LOAD_SET(xaA, xbA, 2);
    __syncthreads();              // L[0] published

    // main loop: 2 tiles per h. Invariant at even sub-iter: buf0 holds tile
    // 2h (ready), B holds tile 2h+1 (landed ~2 sub-iters ago), A holds tile
    // 2h+2 (in flight).
    for (int h = 0; h < 9; ++h) {
        WRITE_SET(xaB, xbB, 2 * h + 1, 1);       // stage odd tile
        if (h < 8) LOAD_SET(xaB, xbB, 2 * h + 3);
        compute(0);                               // tile 2h
        __syncthreads();

        if (h < 8) {
            WRITE_SET(xaA, xbA, 2 * h + 2, 0);   // stage even tile
            if (h < 7) LOAD_SET(xaA, xbA, 2 * h + 4);
        }
        compute(1);                               // tile 2h+1
        __syncthreads();
    }
#undef LOAD_SET
#undef WRITE_SET

    float* gp = Gp + ((size_t)(ks * 6 + tile) << 14);
#pragma unroll
    for (int i = 0; i < 4; ++i) {
        int lr0 = wm * 64 + i * 16 + quad * 4;
#pragma unroll
        for (int j = 0; j < 4; ++j) {
            int lc = wn * 64 + j * 16 + l15;
#pragma unroll
            for (int r = 0; r < 4; ++r)
                gp[(lr0 + r) * 128 + lc] = acc[i][j][r];
        }
    }
}

// ---------------------------------------------------------------- kernel 2
// Reduce partials -> full symmetric G + per-row inverse norm. Zeroes out[0].
__global__ __launch_bounds__(256) void k_red(const float* __restrict__ Gp,
                                             float* __restrict__ G,
                                             float* __restrict__ invn,
                                             float* __restrict__ out) {
    int t    = blockIdx.x * 256 + threadIdx.x;
    if (t == 0) out[0] = 0.0f;
    int tile = t >> 14;
    int idx  = t & 16383;
    int lr   = idx >> 7, lc = idx & 127;
    const float* p = Gp + ((size_t)tile << 14) + idx;
    float s = 0.0f;
#pragma unroll 8
    for (int ks = 0; ks < KSPLIT; ++ks) s += p[(size_t)ks * 98304];
    int tm = (tile < 3) ? 0 : ((tile < 5) ? 1 : 2);
    int tn = (tile < 3) ? tile : ((tile < 5) ? (tile - 2) : 2);
    int a = tm * 128 + lr, b = tn * 128 + lc;
    G[(size_t)a * NR + b] = s;
    G[(size_t)b * NR + a] = s;
    if (a == b) invn[a] = 1.0f / fmaxf(sqrtf(s), 1e-6f);
}

// ---------------------------------------------------------------- kernel 3
// One wave per row a; 1 atomicAdd per block (96 total); pair-slot numerators
// from LDS (R4-verified).
__global__ __launch_bounds__(256) void k_dsum(const float* __restrict__ G,
                                              const float* __restrict__ invn,
                                              float* __restrict__ out) {
    __shared__ float sv[4][NR];          // 6 KB: per-wave row s-values
    __shared__ float tsh[4];
    const int lane = threadIdx.x & 63;
    const int w    = threadIdx.x >> 6;
    const int a    = blockIdx.x * 4 + w;
    float ia  = invn[a];
    int arem  = a & 15;
    float acc = 0.0f;
    for (int b = lane; b < NR; b += 64) {
        float s = G[(size_t)a * NR + b] * ia * invn[b] * 10.0f;
        sv[w][b] = s;
        if ((b & 15) != arem) acc += expf(s);
    }
#pragma unroll
    for (int o = 32; o > 0; o >>= 1) acc += __shfl_down(acc, o);
    if (lane == 0) {
        float Dsa = acc;
        int pr[4];
        if (a < 16)       { pr[0] = 192 + a; pr[1] = a + 16;  pr[2] = a + 192; pr[3] = a + 368; }
        else if (a < 192) { pr[0] = 192 + a; pr[1] = a + 16;  pr[2] = a + 192; pr[3] = a - 16; }
        else if (a < 368) { pr[0] = a - 192; pr[1] = a + 16;  pr[2] = a - 192; pr[3] = a - 16; }
        else              { pr[0] = a - 192; pr[1] = a - 368; pr[2] = a - 192; pr[3] = a - 16; }
        float t = 0.0f;
#pragma unroll
        for (int s = 0; s < 4; ++s) {
            float num = sv[w][pr[s]];    // same value as reloading G (ops identical)
            t += -num + logf(expf(num) + Dsa);
        }
        tsh[w] = t;
    }
    __syncthreads();
    if (threadIdx.x == 0)
        atomicAdd(out, (tsh[0] + tsh[1] + tsh[2] + tsh[3]) * (1.0f / 576.0f));
}

// ---------------------------------------------------------------- launch
extern "C" void kernel_launch(void* const* d_in, const int* in_sizes, int n_in,
                              void* d_out, int out_size, void* d_ws, size_t ws_size,
                              hipStream_t stream) {
    const float* X = (const float*)d_in[0];
    const float* M = (const float*)d_in[1];
    float* out = (float*)d_out;

    char* ws = (char*)d_ws;
    float* Gp   = (float*)ws;                                  // 50.3 MB
    float* G    = Gp + (size_t)KSPLIT * 6 * 16384;             // 590 KB
    float* invn = G + (size_t)NR * NR;

    k_gram<<<dim3(6 * KSPLIT), dim3(256), 0, stream>>>(X, M, Gp);
    k_red<<<dim3(384), dim3(256), 0, stream>>>(Gp, G, invn, out);
    k_dsum<<<dim3(NR / 4), dim3(256), 0, stream>>>(G, invn, out);
}

// Round 6
// 190.842 us; speedup vs baseline: 1.1446x; 1.1446x over previous
//
#include <hip/hip_runtime.h>
#include <hip/hip_bf16.h>
#include <stdint.h>

#define NR 384          // total rows
#define DD 73728        // C*H*W
#define PDV 16          // N_PARTS * N_DATASETS
#define BSV 192         // batch size
#define KSPLIT 128      // split-K factor (768 blocks = 3/CU, fully resident)
#define KCH 576         // DD / KSPLIT
#define BK 32           // K-tile per iteration
#define NIT 18          // KCH / BK
#define RS 40           // LDS row stride bf16 (80 B = 20 banks, 16B-aligned)

typedef __bf16 bf16;
typedef __attribute__((ext_vector_type(4))) __bf16 bf16x4;
typedef __attribute__((ext_vector_type(8))) __bf16 bf16x8;
typedef __attribute__((ext_vector_type(4))) float f32x4;

// ---------------------------------------------------------------- kernel 1
// Fused demean + cast + partial Gram. Main loop is R4-verified VERBATIM
// (R5's depth-2 prefetch regressed: __syncthreads drains vmcnt(0) so extra
// depth is impossible, and +32 VGPR crossed the 128-reg occupancy step).
// R6 change: EPILOGUE ONLY. R5 counters showed WRITE_SIZE = 100 MB = 2x Gp
// (partial-64B-line writebacks from quad-scattered row addressing) plus
// ~13 MB write-allocate fetch. New wave-native Gp layout per tile:
//   addr = w*4096 + (i*4+j)*256 + lane*4 + r
// -> each thread stores acc[i][j] as ONE dwordx4 (16 stores vs 64), each
// wave store is 1024 B contiguous = full lines, zero amplification. k_red
// reads Gp at the SAME linear addresses in the SAME ks order -> G values
// bit-identical; only its scatter into G uses the inverse index map.
__global__ __launch_bounds__(256, 3) void k_gram(const float* __restrict__ X,
                                                 const float* __restrict__ M,
                                                 float* __restrict__ Gp) {
    __shared__ float msh[4 * KCH];       // 9.2 KB
    __shared__ bf16 ash[2][128 * RS];    // 20 KB
    __shared__ bf16 bsh[2][128 * RS];    // 20 KB  (total 49.2 KB, 3/CU OK)
    const int tid  = threadIdx.x;
    const int lane = tid & 63;
    const int w    = tid >> 6;
    const int quad = lane >> 4;
    const int l15  = lane & 15;
    const int wm   = w & 1, wn = w >> 1;
    const int srow = tid >> 3;           // staging row base 0..31
    const int fseg = tid & 7;            // 16B segment within 128B row-chunk
    const int mds  = (srow >> 2) & 3;    // dataset id (same for all p)

    int xcd  = blockIdx.x & 7;
    int g    = blockIdx.x >> 3;
    int tile = g % 6;
    int ks   = xcd + 8 * (g / 6);        // 6 tiles of one ks share an XCD
    int tm = (tile < 3) ? 0 : ((tile < 5) ? 1 : 2);
    int tn = (tile < 3) ? tile : ((tile < 5) ? (tile - 2) : 2);
    const bool diag = (tm == tn);
    const float* Xa = X + (size_t)(tm * 128) * DD;
    const float* Xb = X + (size_t)(tn * 128) * DD;
    size_t k0 = (size_t)ks * KCH;

    // ---- stage M slice once: 4 datasets x 576 floats
    for (int i = tid; i < 4 * 144; i += 256) {
        int ds = i / 144;
        int c  = (i - ds * 144) * 4;
        *(float4*)&msh[ds * KCH + c] = *(const float4*)(M + (size_t)ds * DD + k0 + c);
    }

    f32x4 acc[4][4];
#pragma unroll
    for (int i = 0; i < 4; ++i)
#pragma unroll
        for (int j = 0; j < 4; ++j) acc[i][j] = (f32x4){0.f, 0.f, 0.f, 0.f};

    float4 xa[4], xb[4];                 // single register buffer
    auto load_regs = [&](int it) {
        size_t gk = k0 + (size_t)it * BK + fseg * 4;
#pragma unroll
        for (int p = 0; p < 4; ++p) {
            int row = p * 32 + srow;
            xa[p] = *(const float4*)(Xa + (size_t)row * DD + gk);
            if (!diag) xb[p] = *(const float4*)(Xb + (size_t)row * DD + gk);
        }
    };
    auto write_tiles = [&](int it, int buf) {
        int kc = it * BK + fseg * 4;
        float4 m4 = *(const float4*)&msh[mds * KCH + kc];   // ONE read, all p
#pragma unroll
        for (int p = 0; p < 4; ++p) {
            int row = p * 32 + srow;
            bf16x4 za;
            za[0] = (bf16)(xa[p].x - m4.x); za[1] = (bf16)(xa[p].y - m4.y);
            za[2] = (bf16)(xa[p].z - m4.z); za[3] = (bf16)(xa[p].w - m4.w);
            *(bf16x4*)&ash[buf][row * RS + fseg * 4] = za;
            if (!diag) {
                bf16x4 zb;
                zb[0] = (bf16)(xb[p].x - m4.x); zb[1] = (bf16)(xb[p].y - m4.y);
                zb[2] = (bf16)(xb[p].z - m4.z); zb[3] = (bf16)(xb[p].w - m4.w);
                *(bf16x4*)&bsh[buf][row * RS + fseg * 4] = zb;
            }
        }
    };
    auto compute = [&](int buf) {
        const bf16* bb = diag ? ash[buf] : bsh[buf];
        bf16x8 af[4], bfv[4];
#pragma unroll
        for (int i = 0; i < 4; ++i) {
            int r = wm * 64 + i * 16 + l15;
            af[i] = *(const bf16x8*)&ash[buf][r * RS + quad * 8];
        }
#pragma unroll
        for (int j = 0; j < 4; ++j) {
            int r = wn * 64 + j * 16 + l15;
            bfv[j] = *(const bf16x8*)&bb[r * RS + quad * 8];
        }
#pragma unroll
        for (int i = 0; i < 4; ++i)
#pragma unroll
            for (int j = 0; j < 4; ++j)
                acc[i][j] = __builtin_amdgcn_mfma_f32_16x16x32_bf16(
                    af[i], bfv[j], acc[i][j], 0, 0, 0);
    };

    load_regs(0);
    __syncthreads();              // msh visible
    write_tiles(0, 0);            // vmcnt drains load(0) only
    load_regs(1);
    __syncthreads();              // L[0] published

    for (int it = 0; it < NIT; ++it) {
        int buf = it & 1;
        if (it + 1 < NIT) {
            write_tiles(it + 1, buf ^ 1);    // overlaps compute below
            if (it + 2 < NIT) load_regs(it + 2);
        }
        compute(buf);
        __syncthreads();          // publishes L[buf^1]; frees L[buf]
    }

    // ---- epilogue: wave-native layout, full-line dwordx4 stores
    float* gp = Gp + ((size_t)(ks * 6 + tile) << 14) + w * 4096 + lane * 4;
#pragma unroll
    for (int i = 0; i < 4; ++i)
#pragma unroll
        for (int j = 0; j < 4; ++j)
            *(f32x4*)&gp[(i * 4 + j) * 256] = acc[i][j];
}

// ---------------------------------------------------------------- kernel 2
// Reduce partials -> full symmetric G + per-row inverse norm. Zeroes out[0].
// Reads Gp LINEARLY (same addresses + ks order as before -> bit-identical
// sums); scatters into G via the inverse of k_gram's wave-native map.
__global__ __launch_bounds__(256) void k_red(const float* __restrict__ Gp,
                                             float* __restrict__ G,
                                             float* __restrict__ invn,
                                             float* __restrict__ out) {
    int t    = blockIdx.x * 256 + threadIdx.x;
    if (t == 0) out[0] = 0.0f;
    int tile = t >> 14;
    int idx  = t & 16383;
    const float* p = Gp + ((size_t)tile << 14) + idx;
    float s = 0.0f;
#pragma unroll 8
    for (int ks = 0; ks < KSPLIT; ++ks) s += p[(size_t)ks * 98304];
    // inverse of: addr = w*4096 + (i*4+j)*256 + lane*4 + r
    int r    = idx & 3;
    int lane = (idx >> 2) & 63;
    int ij   = (idx >> 8) & 15;
    int w2   = idx >> 12;
    int wm = w2 & 1, wn = w2 >> 1;
    int i = ij >> 2, j = ij & 3;
    int quad = lane >> 4, l15 = lane & 15;
    int lr = wm * 64 + i * 16 + quad * 4 + r;
    int lc = wn * 64 + j * 16 + l15;
    int tm = (tile < 3) ? 0 : ((tile < 5) ? 1 : 2);
    int tn = (tile < 3) ? tile : ((tile < 5) ? (tile - 2) : 2);
    int a = tm * 128 + lr, b = tn * 128 + lc;
    G[(size_t)a * NR + b] = s;
    G[(size_t)b * NR + a] = s;
    if (a == b) invn[a] = 1.0f / fmaxf(sqrtf(s), 1e-6f);
}

// ---------------------------------------------------------------- kernel 3
// One wave per row a; 1 atomicAdd per block (96 total); pair-slot numerators
// from LDS (R4-verified, verbatim).
__global__ __launch_bounds__(256) void k_dsum(const float* __restrict__ G,
                                              const float* __restrict__ invn,
                                              float* __restrict__ out) {
    __shared__ float sv[4][NR];          // 6 KB: per-wave row s-values
    __shared__ float tsh[4];
    const int lane = threadIdx.x & 63;
    const int w    = threadIdx.x >> 6;
    const int a    = blockIdx.x * 4 + w;
    float ia  = invn[a];
    int arem  = a & 15;
    float acc = 0.0f;
    for (int b = lane; b < NR; b += 64) {
        float s = G[(size_t)a * NR + b] * ia * invn[b] * 10.0f;
        sv[w][b] = s;
        if ((b & 15) != arem) acc += expf(s);
    }
#pragma unroll
    for (int o = 32; o > 0; o >>= 1) acc += __shfl_down(acc, o);
    if (lane == 0) {
        float Dsa = acc;
        int pr[4];
        if (a < 16)       { pr[0] = 192 + a; pr[1] = a + 16;  pr[2] = a + 192; pr[3] = a + 368; }
        else if (a < 192) { pr[0] = 192 + a; pr[1] = a + 16;  pr[2] = a + 192; pr[3] = a - 16; }
        else if (a < 368) { pr[0] = a - 192; pr[1] = a + 16;  pr[2] = a - 192; pr[3] = a - 16; }
        else              { pr[0] = a - 192; pr[1] = a - 368; pr[2] = a - 192; pr[3] = a - 16; }
        float t = 0.0f;
#pragma unroll
        for (int s = 0; s < 4; ++s) {
            float num = sv[w][pr[s]];    // same value as reloading G (ops identical)
            t += -num + logf(expf(num) + Dsa);
        }
        tsh[w] = t;
    }
    __syncthreads();
    if (threadIdx.x == 0)
        atomicAdd(out, (tsh[0] + tsh[1] + tsh[2] + tsh[3]) * (1.0f / 576.0f));
}

// ---------------------------------------------------------------- launch
extern "C" void kernel_launch(void* const* d_in, const int* in_sizes, int n_in,
                              void* d_out, int out_size, void* d_ws, size_t ws_size,
                              hipStream_t stream) {
    const float* X = (const float*)d_in[0];
    const float* M = (const float*)d_in[1];
    float* out = (float*)d_out;

    char* ws = (char*)d_ws;
    float* Gp   = (float*)ws;                                  // 50.3 MB
    float* G    = Gp + (size_t)KSPLIT * 6 * 16384;             // 590 KB
    float* invn = G + (size_t)NR * NR;

    k_gram<<<dim3(6 * KSPLIT), dim3(256), 0, stream>>>(X, M, Gp);
    k_red<<<dim3(384), dim3(256), 0, stream>>>(Gp, G, invn, out);
    k_dsum<<<dim3(NR / 4), dim3(256), 0, stream>>>(G, invn, out);
}